// Round 3
// baseline (859.419 us; speedup 1.0000x reference)
//
#include <hip/hip_runtime.h>
#include <stdint.h>

#define NQ 14
#define DIM 16384
#define NL 6
#define NBATCH 1024
#define PI_F 3.14159265358979323846f
#define BLOCK 512
#define NGATE 70           // (NL-1)*NQ gate angles (layers 1..5)
#define MAXPH 25
#define SLOT_OFF 0xFF

// One fused phase: threads each own the 32-element coset of span{e0,e1,mh0,mh1,mh2}.
struct PhaseDesc {
    uint32_t sgnw[5];   // per-slot sign word: bit r = parity(M(r) & g)
    uint16_t comp[9];   // complement unit vectors (index space, low-2 bits clear)
    uint16_t mh[3];     // hi dims = mask & ~3 (padded with units if < 3 hi gates)
    uint16_t g[5];      // per-slot parity mask (side-0 selector row)
    uint8_t  rml[5];    // slots 0-2: mask&3 ; slots 3-4: full low mask (1..3); 0xFF=off
    uint8_t  widx[5];   // gate angle index in [0, NGATE)
    uint16_t pad;
};
struct PhaseTable {
    PhaseDesc ph[MAXPH];
    int32_t  nph;
    uint16_t gout0, gout1;
};

// ---------------- normalization prepass (unchanged, verified) ----------------
__global__ __launch_bounds__(256) void qs_norm_kernel(const float* __restrict__ x,
                                                      float* __restrict__ nrm)
{
    const int q = blockIdx.x;
    const int tid = threadIdx.x;
    float mn = 3.0e38f, mx = -3.0e38f;
    for (int r = tid; r < NBATCH; r += 256) {
        const float v = x[r * NQ + q];
        mn = fminf(mn, v);
        mx = fmaxf(mx, v);
    }
#pragma unroll
    for (int off = 32; off > 0; off >>= 1) {
        mn = fminf(mn, __shfl_down(mn, off));
        mx = fmaxf(mx, __shfl_down(mx, off));
    }
    __shared__ float smn[4], smx[4];
    const int wid = tid >> 6, lane = tid & 63;
    if (lane == 0) { smn[wid] = mn; smx[wid] = mx; }
    __syncthreads();
    if (tid == 0) {
        mn = fminf(fminf(smn[0], smn[1]), fminf(smn[2], smn[3]));
        mx = fmaxf(fmaxf(smx[0], smx[1]), fmaxf(smx[2], smx[3]));
        nrm[q] = mn;
        nrm[NQ + q] = PI_F / (mx - mn + 1e-8f);
    }
}

// ---------------- register-local gate application ----------------
__device__ __forceinline__ void rot_pair(float& A, float& B, float c, float sv) {
    const float t0 = sv * B;
    const float t1 = sv * A;
    A = fmaf(c, A, -t0);   // side0: c*u - s*v   (sv carries the side sign)
    B = fmaf(c, B,  t1);   // side1: c*v + s*u
}

template<int RM>
__device__ __forceinline__ void apply_gate(float* rs, float c, float svp, float svn,
                                           uint32_t sgnw)
{
    constexpr int MSB = (RM >= 16) ? 16 : (RM >= 8) ? 8 : (RM >= 4) ? 4 : (RM >= 2) ? 2 : 1;
#pragma unroll
    for (int r = 0; r < 32; ++r) {
        if ((r & MSB) == 0) {
            const float sv = ((sgnw >> r) & 1u) ? svn : svp;   // scalar bit -> 1 cndmask
            rot_pair(rs[r], rs[r ^ RM], c, sv);
        }
    }
}

template<int SLOT>
__device__ __forceinline__ void do_slot(const PhaseDesc& ph, const float* csc,
                                        const float* css, uint32_t tb, float* rs)
{
    const uint32_t rml = ph.rml[SLOT];
    if (rml == SLOT_OFF) return;          // wave-uniform
    const int wi = ph.widx[SLOT];
    const float c = csc[wi];
    const float s = css[wi];
    const uint32_t gm = ph.g[SLOT];
    const uint32_t basep = __popc(tb & gm) & 1u;
    const float svp = basep ? -s : s;
    const float svn = -svp;
    const uint32_t sw = ph.sgnw[SLOT];
    if constexpr (SLOT < 3) {
        constexpr int HB = 4 << SLOT;
        switch (rml & 3u) {               // wave-uniform scalar switch
            case 0:  apply_gate<HB | 0>(rs, c, svp, svn, sw); break;
            case 1:  apply_gate<HB | 1>(rs, c, svp, svn, sw); break;
            case 2:  apply_gate<HB | 2>(rs, c, svp, svn, sw); break;
            default: apply_gate<HB | 3>(rs, c, svp, svn, sw); break;
        }
    } else {
        switch (rml) {
            case 1:  apply_gate<1>(rs, c, svp, svn, sw); break;
            case 2:  apply_gate<2>(rs, c, svp, svn, sw); break;
            default: apply_gate<3>(rs, c, svp, svn, sw); break;
        }
    }
}

// ---------------- main kernel: one block per batch element ----------------
__global__ __launch_bounds__(BLOCK) void qs_main_kernel(const float* __restrict__ x,
        const float* __restrict__ w, const float* __restrict__ nrm,
        float* __restrict__ out, const PhaseTable pt)
{
    __shared__ __align__(16) float st[DIM];
    __shared__ float csc[NGATE], css[NGATE];
    __shared__ float red0[BLOCK / 64], red1[BLOCK / 64];
    const int b = blockIdx.x;
    const int tid = threadIdx.x;

    if (tid < NGATE) {                     // gate angle tables (layers 1..5)
        const float h = 0.5f * w[NQ + tid];
        csc[tid] = cosf(h);
        css[tid] = sinf(h);
    }

    // merged encoding + layer-0 -> product state
    float ci[NQ], si[NQ];
#pragma unroll
    for (int q = 0; q < NQ; ++q) {
        const float ang = (x[b * NQ + q] - nrm[q]) * nrm[NQ + q] + w[q];
        const float h = 0.5f * ang;
        ci[q] = cosf(h);
        si[q] = sinf(h);
    }
    for (int i = tid; i < DIM; i += BLOCK) {
        float v = 1.0f;
#pragma unroll
        for (int q = 0; q < NQ; ++q)
            v *= ((i >> (NQ - 1 - q)) & 1) ? si[q] : ci[q];
        st[i] = v;
    }

    // fused gate phases
#pragma unroll 1
    for (int p = 0; p < pt.nph; ++p) {
        __syncthreads();
        const PhaseDesc& ph = pt.ph[p];
        uint32_t tb = 0;
#pragma unroll
        for (int j = 0; j < 9; ++j)
            tb ^= ((tid >> j) & 1) ? (uint32_t)ph.comp[j] : 0u;
        const uint32_t m1 = ph.mh[0], m2 = ph.mh[1], m4 = ph.mh[2];
        uint32_t gi[8];
        gi[0] = tb;        gi[1] = tb ^ m1;   gi[2] = tb ^ m2;   gi[3] = gi[1] ^ m2;
        gi[4] = tb ^ m4;   gi[5] = gi[4] ^ m1; gi[6] = gi[4] ^ m2; gi[7] = gi[5] ^ m2;
        float rs[32];
#pragma unroll
        for (int gq = 0; gq < 8; ++gq) {
            const float4 v = *reinterpret_cast<const float4*>(st + gi[gq]);
            rs[gq * 4 + 0] = v.x; rs[gq * 4 + 1] = v.y;
            rs[gq * 4 + 2] = v.z; rs[gq * 4 + 3] = v.w;
        }
        do_slot<0>(ph, csc, css, tb, rs);
        do_slot<1>(ph, csc, css, tb, rs);
        do_slot<2>(ph, csc, css, tb, rs);
        do_slot<3>(ph, csc, css, tb, rs);
        do_slot<4>(ph, csc, css, tb, rs);
#pragma unroll
        for (int gq = 0; gq < 8; ++gq) {
            float4 v;
            v.x = rs[gq * 4 + 0]; v.y = rs[gq * 4 + 1];
            v.z = rs[gq * 4 + 2]; v.w = rs[gq * 4 + 3];
            *reinterpret_cast<float4*>(st + gi[gq]) = v;
        }
    }
    __syncthreads();

    // expectations (unchanged, verified)
    float e0 = 0.0f, e1 = 0.0f;
    const unsigned g0 = pt.gout0, g1 = pt.gout1;
    for (int i = tid; i < DIM; i += BLOCK) {
        const float a = st[i];
        const float p = a * a;
        e0 += (__popc(i & g0) & 1) ? -p : p;
        e1 += (__popc(i & g1) & 1) ? -p : p;
    }
#pragma unroll
    for (int off = 32; off > 0; off >>= 1) {
        e0 += __shfl_down(e0, off);
        e1 += __shfl_down(e1, off);
    }
    const int wid = tid >> 6, lane = tid & 63;
    if (lane == 0) { red0[wid] = e0; red1[wid] = e1; }
    __syncthreads();
    if (tid == 0) {
        float a0 = 0.0f, a1 = 0.0f;
#pragma unroll
        for (int i = 0; i < BLOCK / 64; ++i) { a0 += red0[i]; a1 += red1[i]; }
        out[b * 2 + 0] = a0;
        out[b * 2 + 1] = a1;
    }
}

// ---------------- host-side GF(2) algebra ----------------
static void bitmat_mul(const uint16_t* A, const uint16_t* B, uint16_t* C) {
    for (int p = 0; p < NQ; ++p) {
        uint16_t r = 0;
        for (int j = 0; j < NQ; ++j)
            if ((A[p] >> j) & 1) r ^= B[j];
        C[p] = r;
    }
}

struct Ech { uint16_t r[16]; int lead[16]; int n; };
static bool ech_add(Ech& e, uint16_t v) {
    for (int i = 0; i < e.n; ++i)
        if ((v >> e.lead[i]) & 1) v ^= e.r[i];
    if (!v) return false;
    int l = 15; while (!((v >> l) & 1)) --l;
    e.r[e.n] = v; e.lead[e.n] = l; e.n++;
    return true;
}

static uint32_t sgnword(const uint16_t* mh, uint16_t g) {
    uint32_t w = 0;
    for (int r = 0; r < 32; ++r) {
        uint16_t Mr = 0;
        if (r & 1)  Mr ^= 1;
        if (r & 2)  Mr ^= 2;
        if (r & 4)  Mr ^= mh[0];
        if (r & 8)  Mr ^= mh[1];
        if (r & 16) Mr ^= mh[2];
        w |= (uint32_t)(__builtin_popcount((unsigned)(Mr & g)) & 1) << r;
    }
    return w;
}

extern "C" void kernel_launch(void* const* d_in, const int* in_sizes, int n_in,
                              void* d_out, int out_size, void* d_ws, size_t ws_size,
                              hipStream_t stream)
{
    const float* x = (const float*)d_in[0];
    const float* w = (const float*)d_in[1];
    float* out = (float*)d_out;
    float* nrm = (float*)d_ws;

    // masks (verified in round 2: absmax 0.0)
    uint16_t mmask[NL][NQ] = {}, gmask[NL][NQ] = {};
    uint16_t U[NQ], IS[NQ], A[NQ], Inv[NQ], T[NQ];
    const uint16_t FULL = (uint16_t)((1u << NQ) - 1u);
    for (int p = 0; p < NQ; ++p) {
        U[p]   = (uint16_t)(FULL & ~((1u << p) - 1u));
        IS[p]  = (uint16_t)((1u << p) | ((p + 1 < NQ) ? (1u << (p + 1)) : 0u));
        A[p]   = (uint16_t)(1u << p);
        Inv[p] = (uint16_t)(1u << p);
    }
    for (int l = 1; l < NL; ++l) {
        bitmat_mul(U, A, T);    for (int p = 0; p < NQ; ++p) A[p] = T[p];
        bitmat_mul(Inv, IS, T); for (int p = 0; p < NQ; ++p) Inv[p] = T[p];
        for (int q = 0; q < NQ; ++q) {
            const int p = NQ - 1 - q;
            uint16_t mm = 0;
            for (int j = 0; j < NQ; ++j) mm |= (uint16_t)(((Inv[j] >> p) & 1u) << j);
            mmask[l][q] = mm;
            gmask[l][q] = A[p];
        }
    }
    PhaseTable pt;
    bitmat_mul(U, A, T);
    pt.gout0 = T[NQ - 1];
    pt.gout1 = T[NQ - 2];

    // partition each layer's 14 commuting gates into fused phases
    pt.nph = 0;
    for (int l = 1; l < NL; ++l) {
        struct HP { int nhi, nlo; int hq[3]; uint16_t hm[3]; int lq[2]; } hp[8];
        int nhp = 0;
        for (int q = 0; q < NQ; ++q) {
            const uint16_t mm = mmask[l][q], mp = (uint16_t)(mm & ~3);
            if (mp == 0) {
                int k = -1;
                for (int i = 0; i < nhp; ++i) if (hp[i].nlo < 2) { k = i; break; }
                if (k < 0) { k = nhp++; hp[k].nhi = hp[k].nlo = 0; }
                hp[k].lq[hp[k].nlo++] = q;
            } else {
                int k = -1;
                for (int i = 0; i < nhp; ++i) {
                    if (hp[i].nhi >= 3) continue;
                    Ech e; e.n = 0;
                    bool ok = true;
                    for (int j = 0; j < hp[i].nhi; ++j) ech_add(e, hp[i].hm[j]);
                    ok = ech_add(e, mp);
                    if (ok) { k = i; break; }
                }
                if (k < 0) { k = nhp++; hp[k].nhi = hp[k].nlo = 0; }
                hp[k].hq[hp[k].nhi] = q;
                hp[k].hm[hp[k].nhi] = mp;
                hp[k].nhi++;
            }
        }
        for (int i = 0; i < nhp && pt.nph < MAXPH; ++i) {
            PhaseDesc& pd = pt.ph[pt.nph++];
            for (int s2 = 0; s2 < 5; ++s2) { pd.rml[s2] = SLOT_OFF; pd.g[s2] = 0; pd.sgnw[s2] = 0; pd.widx[s2] = 0; }
            Ech e; e.n = 0;
            ech_add(e, 1); ech_add(e, 2);
            uint16_t mh[3];
            for (int k = 0; k < hp[i].nhi; ++k) { mh[k] = hp[i].hm[k]; ech_add(e, mh[k]); }
            for (int k = hp[i].nhi; k < 3; ++k)
                for (int j = 2; j < NQ; ++j)
                    if (ech_add(e, (uint16_t)(1u << j))) { mh[k] = (uint16_t)(1u << j); break; }
            pd.mh[0] = mh[0]; pd.mh[1] = mh[1]; pd.mh[2] = mh[2];
            int nc = 0;
            for (int j = 2; j < NQ && nc < 9; ++j)
                if (ech_add(e, (uint16_t)(1u << j))) pd.comp[nc++] = (uint16_t)(1u << j);
            for (int k = 0; k < hp[i].nhi; ++k) {
                const int q = hp[i].hq[k];
                pd.rml[k]  = (uint8_t)(mmask[l][q] & 3);
                pd.g[k]    = gmask[l][q];
                pd.widx[k] = (uint8_t)((l - 1) * NQ + q);
                pd.sgnw[k] = sgnword(mh, gmask[l][q]);
            }
            for (int k = 0; k < hp[i].nlo; ++k) {
                const int q = hp[i].lq[k];
                const int s2 = 3 + k;
                pd.rml[s2]  = (uint8_t)mmask[l][q];
                pd.g[s2]    = gmask[l][q];
                pd.widx[s2] = (uint8_t)((l - 1) * NQ + q);
                pd.sgnw[s2] = sgnword(mh, gmask[l][q]);
            }
        }
    }

    qs_norm_kernel<<<NQ, 256, 0, stream>>>(x, nrm);
    qs_main_kernel<<<NBATCH, BLOCK, 0, stream>>>(x, w, nrm, out, pt);
}

// Round 5
// 75.249 us; speedup vs baseline: 11.4210x; 11.4210x over previous
//
#include <hip/hip_runtime.h>
#include <stdint.h>

#define NQ 14
#define DIM 16384
#define NL 6
#define NBATCH 1024
#define PI_F 3.14159265358979323846f
#define BLOCK 256

// ================= constexpr GF(2) circuit algebra =================
// Circuit structure is input-independent: CNOT chain = linear map I+S.
// After l chains, gate on bit p pairs i with i^mcol(l,p); side-0 selected by
// parity(i & grow(l,p)).  (Equivalent to the round-2-verified host algebra,
// absmax 0.0 — closed forms via Lucas: C(l,k) odd iff (k & ~l)==0.)
constexpr uint32_t mcol(int l, int p) {          // column p of (I+S)^l
    uint32_t m = 0;
    for (int k = 0; k <= p; ++k) if ((k & ~l) == 0) m ^= 1u << (p - k);
    return m;
}
constexpr uint32_t grow(int l, int p) {          // row p of U^l = (I+S)^(16-l)
    uint32_t g = 0;
    const int e = 16 - l;
    for (int k = 0; k + p < NQ; ++k) if ((k & ~e) == 0) g ^= 1u << (p + k);
    return g;
}
constexpr uint32_t popb(uint32_t x) { uint32_t c = 0; while (x) { c += x & 1u; x >>= 1; } return c; }
constexpr int msbit(uint32_t m) { int b = 0; while (m >> (b + 1)) ++b; return b; }
constexpr uint32_t PIW(uint32_t x) { return x ^ (((x >> 6) & 7u) << 2); }  // LDS bank swizzle

template<int GRP> constexpr int pbase()  { return GRP == 0 ? 0 : (GRP == 1 ? 6 : 10); }
template<int GRP> constexpr int ngates() { return GRP == 0 ? 6 : 4; }

// phase basis: {e0,e1} + 4 "hi" vectors (4-aligned)
template<int L, int GRP, int J> constexpr uint32_t mhv() {
    if constexpr (GRP == 0) return 4u << J;                       // e2..e5
    else return mcol(L, pbase<GRP>() + J) & ~3u;                  // gate hi parts
}
template<int L, int GRP, int K> constexpr uint32_t rmv() {        // register-space mask
    constexpr int p = pbase<GRP>() + K;
    if constexpr (GRP == 0) return mcol(L, p);                    // identity basis
    else return (4u << K) | (mcol(L, p) & 3u);
}
constexpr uint32_t mreg(uint32_t r, uint32_t m0, uint32_t m1, uint32_t m2, uint32_t m3) {
    uint32_t M = r & 3u;
    if (r & 4u)  M ^= m0;
    if (r & 8u)  M ^= m1;
    if (r & 16u) M ^= m2;
    if (r & 32u) M ^= m3;
    return M;
}
constexpr uint64_t sgnw_f(uint32_t m0, uint32_t m1, uint32_t m2, uint32_t m3, uint32_t g) {
    uint64_t w = 0;
    for (uint32_t r = 0; r < 64; ++r)
        w |= (uint64_t)(popb(mreg(r, m0, m1, m2, m3) & g) & 1u) << r;
    return w;
}
template<int GRP> constexpr uint32_t cg_of(uint32_t g) {          // tid-parity mask
    if constexpr (GRP == 0) return (g >> 6) & 0xFFu;                              // comp = e6..e13
    else if constexpr (GRP == 1) return ((g >> 2) & 0xFu) | (((g >> 10) & 0xFu) << 4); // e2..e5,e10..e13
    else return (g >> 2) & 0xFFu;                                                 // e2..e9
}
constexpr bool indep6(uint32_t a, uint32_t b, uint32_t c, uint32_t d) {
    uint32_t v[6] = {1u, 2u, a, b, c, d};
    int rank = 0;
    for (int bit = 13; bit >= 0; --bit) {
        int piv = -1;
        for (int i = rank; i < 6; ++i) if ((v[i] >> bit) & 1) { piv = i; break; }
        if (piv < 0) continue;
        uint32_t t = v[piv]; v[piv] = v[rank]; v[rank] = t;
        for (int i = 0; i < 6; ++i) if (i != rank && ((v[i] >> bit) & 1)) v[i] ^= t;
        ++rank;
    }
    return rank == 6;
}

// thread-base address (swizzled) per phase group — comp bases chosen so every
// ds_*_b128 spreads uniformly across banks under PIW
template<int GRP> __device__ __forceinline__ uint32_t ptb_of(uint32_t tid) {
    if constexpr (GRP == 0) return (tid << 6) ^ ((tid & 7u) << 2);
    else if constexpr (GRP == 1) return ((tid & 15u) << 2) | ((tid & 0xF0u) << 6);
    else return (tid << 2) ^ (((tid >> 4) & 7u) << 2);
}

// ================= register-space gate (all compile-time) =================
template<uint32_t RM, uint64_t SG>
__device__ __forceinline__ void gate64(float (&rs)[64], float c, float svp) {
    constexpr uint32_t HB = 1u << msbit(RM);
#pragma unroll
    for (uint32_t r = 0; r < 64; ++r) {
        if ((r & HB) == 0u) {
            const float sv = ((SG >> r) & 1ull) ? -svp : svp;   // compile-time select
            const float u = rs[r], v = rs[r ^ RM];
            const float t0 = sv * v;
            const float t1 = sv * u;
            rs[r]      = fmaf(c, u, -t0);   // side0' = c*s0 - s*s1
            rs[r ^ RM] = fmaf(c, v,  t1);   // side1' = c*s1 + s*s0
        }
    }
}

template<int L, int GRP, int K>
__device__ __forceinline__ void gates_rec(float (&rs)[64], const float* __restrict__ cst,
                                          const float* __restrict__ snt, int tid) {
    if constexpr (K < ngates<GRP>()) {
        constexpr int p = pbase<GRP>() + K;
        constexpr uint32_t g  = grow(L, p);
        constexpr uint32_t RM = rmv<L, GRP, K>();
        constexpr uint64_t SG = sgnw_f(mhv<L,GRP,0>(), mhv<L,GRP,1>(), mhv<L,GRP,2>(), mhv<L,GRP,3>(), g);
        constexpr uint32_t CG = cg_of<GRP>(g);
        constexpr int widx = (L - 1) * NQ + (13 - p);
        const float c = cst[widx];
        const float s = snt[widx];
        const float svp = (__popc((uint32_t)tid & CG) & 1) ? -s : s;
        gate64<RM, SG>(rs, c, svp);
        gates_rec<L, GRP, K + 1>(rs, cst, snt, tid);
    }
}

template<int L, int GRP>
__device__ __forceinline__ void run_gates(float (&rs)[64], const float* __restrict__ cst,
                                          const float* __restrict__ snt, int tid) {
    static_assert(indep6(mhv<L,GRP,0>(), mhv<L,GRP,1>(), mhv<L,GRP,2>(), mhv<L,GRP,3>()), "basis rank");
    gates_rec<L, GRP, 0>(rs, cst, snt, tid);
}

template<int L, int GRP, bool WR>
__device__ __forceinline__ void lds_io(float (&rs)[64], float* st, int tid) {
    constexpr uint32_t m0 = mhv<L,GRP,0>(), m1 = mhv<L,GRP,1>(), m2 = mhv<L,GRP,2>(), m3 = mhv<L,GRP,3>();
    const uint32_t ptb = ptb_of<GRP>((uint32_t)tid);
#pragma unroll
    for (uint32_t gq = 0; gq < 16; ++gq) {
        const uint32_t K = ((gq & 1) ? m0 : 0u) ^ ((gq & 2) ? m1 : 0u) ^
                           ((gq & 4) ? m2 : 0u) ^ ((gq & 8) ? m3 : 0u);
        const uint32_t a = ptb ^ PIW(K);                        // folds: PIW(const)
        if constexpr (WR) *reinterpret_cast<float4*>(st + a) = *reinterpret_cast<const float4*>(&rs[gq * 4]);
        else *reinterpret_cast<float4*>(&rs[gq * 4]) = *reinterpret_cast<const float4*>(st + a);
    }
}

template<int L, int GRP>
__device__ __forceinline__ void mid_phase(float (&rs)[64], float* st,
        const float* __restrict__ cst, const float* __restrict__ snt, int tid) {
    lds_io<L, GRP, false>(rs, st, tid);
    run_gates<L, GRP>(rs, cst, snt, tid);
    lds_io<L, GRP, true>(rs, st, tid);
    __syncthreads();
}

// ================= prepass: min/scale + gate cos/sin tables =================
__global__ __launch_bounds__(256) void qs_norm_kernel(const float* __restrict__ x,
                                                      const float* __restrict__ w,
                                                      float* __restrict__ ws) {
    const int q = blockIdx.x;
    const int tid = threadIdx.x;
    float mn = 3.0e38f, mx = -3.0e38f;
    for (int r = tid; r < NBATCH; r += 256) {
        const float v = x[r * NQ + q];
        mn = fminf(mn, v);
        mx = fmaxf(mx, v);
    }
#pragma unroll
    for (int off = 32; off > 0; off >>= 1) {
        mn = fminf(mn, __shfl_down(mn, off));
        mx = fmaxf(mx, __shfl_down(mx, off));
    }
    __shared__ float smn[4], smx[4];
    const int wid = tid >> 6, lane = tid & 63;
    if (lane == 0) { smn[wid] = mn; smx[wid] = mx; }
    __syncthreads();
    if (tid == 0) {
        mn = fminf(fminf(smn[0], smn[1]), fminf(smn[2], smn[3]));
        mx = fmaxf(fmaxf(smx[0], smx[1]), fmaxf(smx[2], smx[3]));
        ws[q] = mn;
        ws[NQ + q] = PI_F / (mx - mn + 1e-8f);
    }
    if (blockIdx.x == 0) {
        for (int t = tid; t < (NL - 1) * NQ; t += 256) {
            const float h = 0.5f * w[NQ + t];
            ws[32 + t]  = cosf(h);
            ws[112 + t] = sinf(h);
        }
    }
}

// ================= main: one block per batch element =================
__global__ __launch_bounds__(BLOCK) void qs_main_kernel(
        const float* __restrict__ x, const float* __restrict__ w,
        const float* __restrict__ nrm, const float* __restrict__ cst,
        const float* __restrict__ snt, float* __restrict__ out) {
    __shared__ __align__(16) float st[DIM];
    __shared__ float red0[4], red1[4];
    const int tid = threadIdx.x;
    const int b = blockIdx.x;

    // merged encoding + layer-0 angles (verified)
    float ci[NQ], si[NQ];
#pragma unroll
    for (int q = 0; q < NQ; ++q) {
        const float ang = (x[b * NQ + q] - nrm[q]) * nrm[NQ + q] + w[q];
        const float h = 0.5f * ang;
        ci[q] = cosf(h);
        si[q] = sinf(h);
    }
    // product state directly in registers, phase-(1,0) layout: i=(tid<<6)|r, bit b ↔ qubit 13-b
    float H = 1.0f;
#pragma unroll
    for (int q = 0; q < 8; ++q) H *= ((tid >> (7 - q)) & 1) ? si[q] : ci[q];
    float p2[4], p4[16], hh[4];
#pragma unroll
    for (int j = 0; j < 4; ++j) p2[j] = ((j & 1) ? si[13] : ci[13]) * ((j & 2) ? si[12] : ci[12]);
#pragma unroll
    for (int j = 0; j < 16; ++j) p4[j] = p2[j & 3] * ((j & 4) ? si[11] : ci[11]) * ((j & 8) ? si[10] : ci[10]);
#pragma unroll
    for (int j = 0; j < 4; ++j) hh[j] = H * ((j & 1) ? si[9] : ci[9]) * ((j & 2) ? si[8] : ci[8]);
    alignas(16) float rs[64];
#pragma unroll
    for (int r = 0; r < 64; ++r) rs[r] = p4[r & 15] * hh[r >> 4];

    // 15 phases, 3 per layer; first has no read, last has no write
    run_gates<1, 0>(rs, cst, snt, tid); lds_io<1, 0, true>(rs, st, tid); __syncthreads();
    mid_phase<1, 1>(rs, st, cst, snt, tid);
    mid_phase<1, 2>(rs, st, cst, snt, tid);
    mid_phase<2, 0>(rs, st, cst, snt, tid);
    mid_phase<2, 1>(rs, st, cst, snt, tid);
    mid_phase<2, 2>(rs, st, cst, snt, tid);
    mid_phase<3, 0>(rs, st, cst, snt, tid);
    mid_phase<3, 1>(rs, st, cst, snt, tid);
    mid_phase<3, 2>(rs, st, cst, snt, tid);
    mid_phase<4, 0>(rs, st, cst, snt, tid);
    mid_phase<4, 1>(rs, st, cst, snt, tid);
    mid_phase<4, 2>(rs, st, cst, snt, tid);
    mid_phase<5, 0>(rs, st, cst, snt, tid);
    mid_phase<5, 1>(rs, st, cst, snt, tid);
    lds_io<5, 2, false>(rs, st, tid);
    run_gates<5, 2>(rs, cst, snt, tid);

    // expectations in-register: sign = bit13/bit12 of element index (gout = e13/e12,
    // grp2 thread-base has no bits >=10 -> compile-time per register)
    constexpr uint32_t f0 = mhv<5,2,0>(), f1 = mhv<5,2,1>(), f2 = mhv<5,2,2>(), f3 = mhv<5,2,3>();
    float e0 = 0.0f, e1 = 0.0f;
#pragma unroll
    for (uint32_t r = 0; r < 64; ++r) {
        const uint32_t M = mreg(r, f0, f1, f2, f3);
        const float v = rs[r];
        e0 = fmaf(v, ((M >> 13) & 1u) ? -v : v, e0);
        e1 = fmaf(v, ((M >> 12) & 1u) ? -v : v, e1);
    }
#pragma unroll
    for (int off = 32; off > 0; off >>= 1) {
        e0 += __shfl_down(e0, off);
        e1 += __shfl_down(e1, off);
    }
    const int wid = tid >> 6, lane = tid & 63;
    if (lane == 0) { red0[wid] = e0; red1[wid] = e1; }
    __syncthreads();
    if (tid == 0) {
        out[b * 2 + 0] = red0[0] + red0[1] + red0[2] + red0[3];
        out[b * 2 + 1] = red1[0] + red1[1] + red1[2] + red1[3];
    }
}

extern "C" void kernel_launch(void* const* d_in, const int* in_sizes, int n_in,
                              void* d_out, int out_size, void* d_ws, size_t ws_size,
                              hipStream_t stream) {
    const float* x = (const float*)d_in[0];   // (1024, 14) f32
    const float* w = (const float*)d_in[1];   // (6, 14) f32
    float* out = (float*)d_out;               // (1024, 2) f32
    float* ws = (float*)d_ws;                 // [0..27] min/scale, [32..101] cos, [112..181] sin

    qs_norm_kernel<<<NQ, 256, 0, stream>>>(x, w, ws);
    qs_main_kernel<<<NBATCH, BLOCK, 0, stream>>>(x, w, ws, ws + 32, ws + 112, out);
}